// Round 8
// baseline (19388.971 us; speedup 1.0000x reference)
//
#include <hip/hip_runtime.h>
#include <math.h>

// Problem constants
#define BB 16
#define TT 128
#define F_IN 240
#define E_DIM 1024
#define HH 320
#define G4 1280
#define JHD 512
#define VV 29
#define BLANKV 28
#define MAXSYM 3
#define LBUF (TT*MAXSYM)

#define NB 32          // decode blocks (lockstep participants)
#define GRID_TOTAL 256 // decode blocks + heater blocks (keep clocks up)
#define ROWS 10
#define JBLK 16
#define LPITCH 324     // LDS row pitch (floats, 16B-aligned)

// Workspace layout (float offsets)
#define OFF_FPROJ 0ul                        // 2048*512
#define OFF_WJHR  1048576ul                  // 512*320
#define OFF_EP    (OFF_WJHR + 163840ul)      // 29*1280
#define OFF_B1    (OFF_EP + 37120ul)         // 1280
#define OFF_MA    (OFF_B1 + 1280ul)          // 16*320 pending h0
#define OFF_MB    (OFF_MA + 5120ul)          // 16*320 pending h1
#define OFF_PL    (OFF_MB + 5120ul)          // 32*464 partial logits
#define OFF_SYNC  (OFF_PL + 14848ul)         // 2048 ints: tags + done flag

typedef float f32x4 __attribute__((ext_vector_type(4)));

__device__ __forceinline__ float sigmoidf_(float x) {
    return 1.0f / (1.0f + expf(-x));
}
__device__ __forceinline__ float ld_agent(const float* p) {
    return __hip_atomic_load(p, __ATOMIC_RELAXED, __HIP_MEMORY_SCOPE_AGENT);
}
__device__ __forceinline__ void st_agent(float* p, float v) {
    __hip_atomic_store(p, v, __ATOMIC_RELAXED, __HIP_MEMORY_SCOPE_AGENT);
}
__device__ __forceinline__ int ld_agent_i(const int* p) {
    return __hip_atomic_load(p, __ATOMIC_RELAXED, __HIP_MEMORY_SCOPE_AGENT);
}
__device__ __forceinline__ void st_agent_i(int* p, int v) {
    __hip_atomic_store(p, v, __ATOMIC_RELAXED, __HIP_MEMORY_SCOPE_AGENT);
}
__device__ __forceinline__ f32x4 ld4_sc(const float* p) {
    f32x4 v;
    asm volatile("global_load_dwordx4 %0, %1, off sc0 sc1\n\t"
                 "s_waitcnt vmcnt(0)"
                 : "=&v"(v) : "v"(p) : "memory");
    return v;
}
__device__ __forceinline__ void ld4x2_sc(const float* p0, const float* p1,
                                         f32x4& a, f32x4& b) {
    asm volatile("global_load_dwordx4 %0, %2, off sc0 sc1\n\t"
                 "global_load_dwordx4 %1, %3, off sc0 sc1\n\t"
                 "s_waitcnt vmcnt(0)"
                 : "=&v"(a), "=&v"(b) : "v"(p0), "v"(p1) : "memory");
}

// ---- Prep: WjhR[j][k] = Wj1[1024+k][j]; b1 = bih1 + bhh1 ----
__global__ void prep_t_kernel(const float* __restrict__ Wj1,
                              const float* __restrict__ bih1,
                              const float* __restrict__ bhh1,
                              float* __restrict__ WjhR, float* __restrict__ b1) {
    int idx = blockIdx.x * 256 + threadIdx.x;
    if (idx < 163840) {
        int j = idx / 320, k = idx - j * 320;
        WjhR[idx] = Wj1[(size_t)(1024 + k) * JHD + j];
        return;
    }
    int i2 = idx - 163840;
    if (i2 < G4) b1[i2] = bih1[i2] + bhh1[i2];
}

// ---- Prep: EP[v][j] = embed[v]@Wih0[j,:] + bih0[j]+bhh0[j]; row 28 = bias only
__global__ void ep_kernel(const float* __restrict__ embed,
                          const float* __restrict__ Wih0,
                          const float* __restrict__ bih0,
                          const float* __restrict__ bhh0,
                          float* __restrict__ EP) {
    __shared__ __align__(16) float es[HH];
    int v = blockIdx.x;
    for (int k = threadIdx.x; k < HH; k += 256)
        es[k] = (v < VV - 1) ? embed[v * HH + k] : 0.0f;
    __syncthreads();
    for (int j = threadIdx.x; j < G4; j += 256) {
        float acc = bih0[j] + bhh0[j];
        if (v < VV - 1) {
            const float4* wr = (const float4*)(Wih0 + (size_t)j * HH);
            const float4* ev = (const float4*)es;
            #pragma unroll 4
            for (int k4 = 0; k4 < HH / 4; ++k4) {
                float4 w = wr[k4], e = ev[k4];
                acc += w.x * e.x + w.y * e.y + w.z * e.z + w.w * e.w;
            }
        }
        EP[v * G4 + j] = acc;
    }
}

// ---- Encoder + F_proj fused ----
__global__ __launch_bounds__(512) void enc_fproj_kernel(
    const float* __restrict__ x, const float* __restrict__ Wenc,
    const float* __restrict__ benc, const float* __restrict__ Wj1,
    const float* __restrict__ bj1,
    float* __restrict__ logits_out, float* __restrict__ Fproj) {
    __shared__ float xs[8][F_IN];
    __shared__ float ls[8][E_DIM];
    int row0 = blockIdx.x * 8;
    int tid = threadIdx.x;
    for (int i = tid; i < 8 * F_IN; i += 512)
        xs[i / F_IN][i % F_IN] = x[(size_t)row0 * F_IN + i];
    __syncthreads();
    for (int j = tid; j < E_DIM; j += 512) {
        float acc[8];
        float bv = benc[j];
        #pragma unroll
        for (int r = 0; r < 8; ++r) acc[r] = bv;
        for (int k = 0; k < F_IN; ++k) {
            float w = Wenc[(size_t)k * E_DIM + j];
            #pragma unroll
            for (int r = 0; r < 8; ++r) acc[r] += xs[r][k] * w;
        }
        #pragma unroll
        for (int r = 0; r < 8; ++r) {
            ls[r][j] = acc[r];
            logits_out[(size_t)(row0 + r) * E_DIM + j] = acc[r];
        }
    }
    __syncthreads();
    {
        int j = tid;
        float acc[8];
        float bv = bj1[j];
        #pragma unroll
        for (int r = 0; r < 8; ++r) acc[r] = bv;
        for (int k = 0; k < E_DIM; ++k) {
            float w = Wj1[(size_t)k * JHD + j];
            #pragma unroll
            for (int r = 0; r < 8; ++r) acc[r] += ls[r][k] * w;
        }
        #pragma unroll
        for (int r = 0; r < 8; ++r) Fproj[(size_t)(row0 + r) * JHD + j] = acc[r];
    }
}

// ---- Init: zero sync words; labels=-1; out_lens passthrough ----
__global__ void init_kernel(const int* __restrict__ lens, float* ws,
                            float* __restrict__ out_lens_out,
                            float* __restrict__ labels_out) {
    int tid = threadIdx.x;
    int* sync = (int*)(ws + OFF_SYNC);
    for (int i = tid; i < 2048; i += 1024) sync[i] = 0;
    for (int i = tid; i < BB * LBUF; i += 1024) labels_out[i] = -1.0f;
    if (tid < BB) out_lens_out[tid] = (float)lens[tid];
}

// ---- Persistent lockstep decoder: 32 decode blocks + 224 heater blocks ----
// Decode protocol (identical to round 7): A(tag)->B(tag)->C(tag)->replicated D.
// Heater blocks run pure-VALU FMA to hold clocks at boost; exit on done flag.
__global__ __launch_bounds__(1024) void decode_persistent(
    const int* __restrict__ lens,
    const float* __restrict__ Fproj,
    const float* __restrict__ W0,    // Whh0 [1280][320]
    const float* __restrict__ W1a,   // Wih1 [1280][320]
    const float* __restrict__ W1b,   // Whh1 [1280][320]
    const float* __restrict__ WjhR,  // [512][320]
    const float* __restrict__ Wj2,   // [512][29]
    const float* __restrict__ EP, const float* __restrict__ b1,
    const float* __restrict__ bj2,
    float* MA, float* MB, float* PL, int* syncw,
    float* __restrict__ labels_out, float* __restrict__ counts_out) {

    const int tid = threadIdx.x;
    const int blk = blockIdx.x;
    int* doneF = syncw + 1536;

    if (blk >= NB) {
        // ---------- heater: dependent FMA chain, poll done flag ----------
        float a = 1.0f + (float)tid * 1e-7f;
        float m = 0.9999999f;
        float c = 0.0f;
        while (ld_agent_i(doneF) == 0) {
            #pragma unroll 32
            for (int i = 0; i < 2048; ++i) c = __builtin_fmaf(c, m, a);
            asm volatile("" :: "v"(c));   // keep the chain live
        }
        asm volatile("" :: "v"(c));
        return;
    }

    int* Atag = syncw;            // 32 tags, 64B apart
    int* Btag = syncw + 512;
    int* Ctag = syncw + 1024;

    extern __shared__ float dyn[];
    float* h0c = dyn;                    // [16][LPITCH] current h0
    float* h1c = dyn + 16 * LPITCH;      // current h1
    float* h0p = dyn + 32 * LPITCH;      // staged pending h0
    float* h1p = dyn + 48 * LPITCH;      // staged pending h1

    __shared__ float sh_jh[16 * 17];
    __shared__ float sh_lg[16 * 30];
    __shared__ int sh_dec[16];
    __shared__ int lastL[16], cntL[16], contL[16], lenL[16], emitL[16];
    __shared__ int sMaxL;

    for (int i = tid; i < 32 * LPITCH; i += 1024) { h0c[i] = 0.f; h1c[i] = 0.f; }
    if (tid < 16) {
        lastL[tid] = BLANKV; cntL[tid] = 0; contL[tid] = 0;
        lenL[tid] = lens[tid];
    }
    if (tid == 0) {
        int m = 0;
        for (int i = 0; i < BB; ++i) m = max(m, lens[i]);
        sMaxL = m;
    }
    __syncthreads();
    const int maxL = sMaxL;

    // matvec lanes (A/B): tid<640: b | ks<<4 | rh<<6 (shfl 16,32 reduces ks)
    const int b  = tid & 15;
    const int ks = (tid >> 4) & 3;
    const int rh = tid >> 6;
    const bool mv = tid < 640;
    const int row = blk * ROWS + rh;
    const int kf = ks * 80;

    float c0cur = 0.f, c1cur = 0.f, c0p = 0.f, c1p = 0.f;
    float g1p0 = 0.f, g1p1 = 0.f, g1p2 = 0.f, g1p3 = 0.f;

    for (int slot = 0; slot < 3 * maxL; ++slot) {
        const int t = slot / 3;
        const int s = slot - t * 3;
        const int e = slot + 1;

        // ===== Phase A: gates0 = Whh0@h0cur (+EP); also g1p = Whh1@h1cur =====
        if (mv) {
            const float4* h0v = (const float4*)(h0c + b * LPITCH + kf);
            const float4* h1v = (const float4*)(h1c + b * LPITCH + kf);
            const float* w0 = W0  + (size_t)row * 320 + kf;
            const float* wb = W1b + (size_t)row * 320 + kf;
            float g0[4] = {0.f, 0.f, 0.f, 0.f};
            float g1[4] = {0.f, 0.f, 0.f, 0.f};
            #pragma unroll 5
            for (int u = 0; u < 20; ++u) {
                float4 h0 = h0v[u], h1 = h1v[u];
                #pragma unroll
                for (int g = 0; g < 4; ++g) {
                    float4 w = *(const float4*)(w0 + (size_t)g * 102400 + u * 4);
                    g0[g] += h0.x * w.x + h0.y * w.y + h0.z * w.z + h0.w * w.w;
                    float4 v2 = *(const float4*)(wb + (size_t)g * 102400 + u * 4);
                    g1[g] += h1.x * v2.x + h1.y * v2.y + h1.z * v2.z + h1.w * v2.w;
                }
            }
            g1p0 = g1[0]; g1p1 = g1[1]; g1p2 = g1[2]; g1p3 = g1[3];
            #pragma unroll
            for (int g = 0; g < 4; ++g) {
                g0[g] += __shfl_xor(g0[g], 16);
                g0[g] += __shfl_xor(g0[g], 32);
            }
            if (ks == 0) {
                const float* ep = EP + (size_t)lastL[b] * G4 + row;
                float xi = g0[0] + ep[0];
                float xf = g0[1] + ep[320];
                float xg = g0[2] + ep[640];
                float xo = g0[3] + ep[960];
                c0p = sigmoidf_(xf) * c0cur + sigmoidf_(xi) * tanhf(xg);
                st_agent(MA + b * 320 + row, sigmoidf_(xo) * tanhf(c0p));
            }
        }
        asm volatile("s_waitcnt vmcnt(0)" ::: "memory");
        __syncthreads();
        if (tid == 0) st_agent_i(Atag + blk * 16, e);

        // ===== Phase B: gates1 = g1p + Wih1@h0p + b1 =====
        if (tid < 64) {
            const int* tp = Atag + (tid & 31) * 16;
            while (__ballot((tid < 32) && (ld_agent_i(tp) < e)) != 0ull) { }
        }
        __syncthreads();
        {   // stage MA -> h0p: 1280 vec4
            if (tid < 256) {
                f32x4 v0, v1;
                int i1 = tid + 1024;
                ld4x2_sc(MA + tid * 4, MA + i1 * 4, v0, v1);
                int ib0 = tid / 80, k0 = tid - ib0 * 80;
                int ib1 = i1 / 80,  k1 = i1 - ib1 * 80;
                *(f32x4*)(h0p + ib0 * LPITCH + k0 * 4) = v0;
                *(f32x4*)(h0p + ib1 * LPITCH + k1 * 4) = v1;
            } else {
                f32x4 v0 = ld4_sc(MA + tid * 4);
                int ib0 = tid / 80, k0 = tid - ib0 * 80;
                *(f32x4*)(h0p + ib0 * LPITCH + k0 * 4) = v0;
            }
        }
        __syncthreads();
        if (mv) {
            const float4* hv = (const float4*)(h0p + b * LPITCH + kf);
            const float* wa = W1a + (size_t)row * 320 + kf;
            float g1[4] = {g1p0, g1p1, g1p2, g1p3};
            #pragma unroll 5
            for (int u = 0; u < 20; ++u) {
                float4 h = hv[u];
                #pragma unroll
                for (int g = 0; g < 4; ++g) {
                    float4 w = *(const float4*)(wa + (size_t)g * 102400 + u * 4);
                    g1[g] += h.x * w.x + h.y * w.y + h.z * w.z + h.w * w.w;
                }
            }
            #pragma unroll
            for (int g = 0; g < 4; ++g) {
                g1[g] += __shfl_xor(g1[g], 16);
                g1[g] += __shfl_xor(g1[g], 32);
            }
            if (ks == 0) {
                float xi = g1[0] + b1[0 * 320 + row];
                float xf = g1[1] + b1[1 * 320 + row];
                float xg = g1[2] + b1[2 * 320 + row];
                float xo = g1[3] + b1[3 * 320 + row];
                c1p = sigmoidf_(xf) * c1cur + sigmoidf_(xi) * tanhf(xg);
                st_agent(MB + b * 320 + row, sigmoidf_(xo) * tanhf(c1p));
            }
        }
        asm volatile("s_waitcnt vmcnt(0)" ::: "memory");
        __syncthreads();
        if (tid == 0) st_agent_i(Btag + blk * 16, e);

        // ===== Phase C: jh slice (16 j) + partial logits =====
        if (tid < 64) {
            const int* tp = Btag + (tid & 31) * 16;
            while (__ballot((tid < 32) && (ld_agent_i(tp) < e)) != 0ull) { }
        }
        __syncthreads();
        {   // stage MB -> h1p: 1280 vec4
            if (tid < 256) {
                f32x4 v0, v1;
                int i1 = tid + 1024;
                ld4x2_sc(MB + tid * 4, MB + i1 * 4, v0, v1);
                int ib0 = tid / 80, k0 = tid - ib0 * 80;
                int ib1 = i1 / 80,  k1 = i1 - ib1 * 80;
                *(f32x4*)(h1p + ib0 * LPITCH + k0 * 4) = v0;
                *(f32x4*)(h1p + ib1 * LPITCH + k1 * 4) = v1;
            } else {
                f32x4 v0 = ld4_sc(MB + tid * 4);
                int ib0 = tid / 80, k0 = tid - ib0 * 80;
                *(f32x4*)(h1p + ib0 * LPITCH + k0 * 4) = v0;
            }
        }
        __syncthreads();
        if (tid < 512) {
            int ks2 = (tid >> 4) & 3, j5 = tid >> 6;   // 0..7
            int j0 = blk * JBLK + j5, j1_ = j0 + 8;
            const float4* hv = (const float4*)(h1p + b * LPITCH + ks2 * 80);
            const float* wc0 = WjhR + (size_t)j0 * 320 + ks2 * 80;
            const float* wc1 = WjhR + (size_t)j1_ * 320 + ks2 * 80;
            float p0 = 0.f, p1 = 0.f;
            #pragma unroll 5
            for (int u = 0; u < 20; ++u) {
                float4 h = hv[u];
                float4 w = *(const float4*)(wc0 + u * 4);
                p0 += h.x * w.x + h.y * w.y + h.z * w.z + h.w * w.w;
                float4 w2 = *(const float4*)(wc1 + u * 4);
                p1 += h.x * w2.x + h.y * w2.y + h.z * w2.z + h.w * w2.w;
            }
            p0 += __shfl_xor(p0, 16); p0 += __shfl_xor(p0, 32);
            p1 += __shfl_xor(p1, 16); p1 += __shfl_xor(p1, 32);
            if (ks2 == 0) {
                const float* fp = Fproj + ((size_t)(b * TT + t)) * JHD;
                sh_jh[b * 17 + j5]     = fmaxf(p0 + fp[j0], 0.f);
                sh_jh[b * 17 + j5 + 8] = fmaxf(p1 + fp[j1_], 0.f);
            }
        }
        __syncthreads();
        if (tid < 464) {
            int b2 = tid / 29, v = tid - b2 * 29;
            float p = 0.f;
            #pragma unroll
            for (int jl = 0; jl < 16; ++jl)
                p += sh_jh[b2 * 17 + jl] * Wj2[(size_t)(blk * JBLK + jl) * VV + v];
            st_agent(PL + blk * 464 + tid, p);
        }
        asm volatile("s_waitcnt vmcnt(0)" ::: "memory");
        __syncthreads();
        if (tid == 0) st_agent_i(Ctag + blk * 16, e);

        // ===== Phase D (replicated in every block): reduce + argmax =====
        if (tid < 64) {
            const int* tp = Ctag + (tid & 31) * 16;
            while (__ballot((tid < 32) && (ld_agent_i(tp) < e)) != 0ull) { }
        }
        __syncthreads();
        if (tid < 464) {
            int b2 = tid / 29, v = tid - b2 * 29;
            float t0[NB];
            #pragma unroll
            for (int r = 0; r < NB; ++r)
                t0[r] = ld_agent(PL + r * 464 + tid);
            float acc = bj2[v];
            #pragma unroll
            for (int r = 0; r < NB; ++r) acc += t0[r];
            sh_lg[b2 * 30 + v] = acc;
        }
        __syncthreads();
        if (tid < 16) {
            float best = sh_lg[tid * 30];
            int k = 0;
            #pragma unroll
            for (int v = 1; v < VV; ++v) {
                float x = sh_lg[tid * 30 + v];
                if (x > best) { best = x; k = v; }
            }
            bool active = (t < lenL[tid]) && (s == 0 || contL[tid]);
            bool emit = active && (k != BLANKV);
            sh_dec[tid] = emit ? k : 63;
            if (emit && blk == 0)
                labels_out[(size_t)tid * LBUF + cntL[tid]] = (float)k;
        }
        __syncthreads();

        // ===== Commit: flags + LDS-to-LDS copy, zero global traffic =====
        if (tid < 16) {
            int code = sh_dec[tid];
            int em = (code != 63);
            emitL[tid] = em;
            if (em) { lastL[tid] = code; cntL[tid] += 1; contL[tid] = 1; }
            else    { contL[tid] = 0; }
        }
        __syncthreads();
        for (int idx = tid; idx < 1280; idx += 1024) {
            int ib = idx / 80, q = idx - ib * 80;
            if (emitL[ib]) {
                ((float4*)(h0c + ib * LPITCH))[q] = ((const float4*)(h0p + ib * LPITCH))[q];
                ((float4*)(h1c + ib * LPITCH))[q] = ((const float4*)(h1p + ib * LPITCH))[q];
            }
        }
        if (mv && ks == 0 && emitL[b]) { c0cur = c0p; c1cur = c1p; }
        __syncthreads();
    }

    if (blk == 0 && tid < 16) counts_out[tid] = (float)cntL[tid];
    // release heaters
    __syncthreads();
    if (tid == 0) st_agent_i(doneF, 1);
}

extern "C" void kernel_launch(void* const* d_in, const int* in_sizes, int n_in,
                              void* d_out, int out_size, void* d_ws, size_t ws_size,
                              hipStream_t stream) {
    const float* x      = (const float*)d_in[0];
    const int*   lens   = (const int*)d_in[1];
    const float* Wenc   = (const float*)d_in[2];
    const float* benc   = (const float*)d_in[3];
    const float* embed  = (const float*)d_in[4];
    const float* Wih0   = (const float*)d_in[5];
    const float* Whh0   = (const float*)d_in[6];
    const float* bih0   = (const float*)d_in[7];
    const float* bhh0   = (const float*)d_in[8];
    const float* Wih1   = (const float*)d_in[9];
    const float* Whh1   = (const float*)d_in[10];
    const float* bih1   = (const float*)d_in[11];
    const float* bhh1   = (const float*)d_in[12];
    const float* Wj1    = (const float*)d_in[13];
    const float* bj1    = (const float*)d_in[14];
    const float* Wj2    = (const float*)d_in[15];
    const float* bj2    = (const float*)d_in[16];

    float* out = (float*)d_out;
    float* logits_out   = out;
    float* out_lens_out = out + (size_t)BB * TT * E_DIM;
    float* labels_out   = out_lens_out + BB;
    float* counts_out   = labels_out + (size_t)BB * LBUF;

    float* ws    = (float*)d_ws;
    float* Fproj = ws + OFF_FPROJ;
    float* WjhR  = ws + OFF_WJHR;
    float* EP    = ws + OFF_EP;
    float* b1    = ws + OFF_B1;
    float* MA    = ws + OFF_MA;
    float* MB    = ws + OFF_MB;
    float* PL    = ws + OFF_PL;
    int*   syncw = (int*)(ws + OFF_SYNC);

    // dynamic LDS: 64 rows * LPITCH floats = 82,944 B (> 64 KB default cap)
    const int dynBytes = 64 * LPITCH * 4;
    hipFuncSetAttribute((const void*)decode_persistent,
                        hipFuncAttributeMaxDynamicSharedMemorySize, dynBytes);

    {
        int total = 163840 + G4;
        prep_t_kernel<<<(total + 255) / 256, 256, 0, stream>>>(Wj1, bih1, bhh1, WjhR, b1);
    }
    ep_kernel<<<VV, 256, 0, stream>>>(embed, Wih0, bih0, bhh0, EP);
    enc_fproj_kernel<<<(BB * TT) / 8, 512, 0, stream>>>(x, Wenc, benc, Wj1, bj1,
                                                        logits_out, Fproj);
    init_kernel<<<1, 1024, 0, stream>>>(lens, ws, out_lens_out, labels_out);
    decode_persistent<<<GRID_TOTAL, 1024, dynBytes, stream>>>(
        lens, Fproj, Whh0, Wih1, Whh1, WjhR, Wj2, EP, b1, bj2,
        MA, MB, PL, syncw, labels_out, counts_out);
}

// Round 10
// 10364.316 us; speedup vs baseline: 1.8707x; 1.8707x over previous
//
#include <hip/hip_runtime.h>
#include <math.h>

// Problem constants
#define BB 16
#define TT 128
#define F_IN 240
#define E_DIM 1024
#define HH 320
#define G4 1280
#define JHD 512
#define VV 29
#define BLANKV 28
#define MAXSYM 3
#define LBUF (TT*MAXSYM)

#define GROUPS 8
#define RPG 20            // roles per group
#define NBLK (GROUPS*RPG) // 160 blocks
#define HR 16             // h-rows per role (320/20)
#define JR 32             // joint rows per C-role
#define CROLES 16         // roles doing phase C (16*32=512)

// Workspace layout (float offsets)
#define OFF_FPROJ 0ul                        // 2048*512
#define OFF_WJHR  1048576ul                  // 512*320
#define OFF_EP    (OFF_WJHR + 163840ul)      // 29*1280
#define OFF_B1    (OFF_EP + 37120ul)         // 1280
#define OFF_WJ2T  (OFF_B1 + 1280ul)          // 29*512 = 14848
#define OFF_MA    (OFF_WJ2T + 14848ul)       // [8][2][320] = 5120
#define OFF_MB    (OFF_MA + 5120ul)          // 5120
#define OFF_JH    (OFF_MB + 5120ul)          // [8][2][512] = 8192
#define OFF_SYNC  (OFF_JH + 8192ul)          // 2048 ints

typedef float f32x4 __attribute__((ext_vector_type(4)));

__device__ __forceinline__ float sigmoidf_(float x) {
    return 1.0f / (1.0f + expf(-x));
}
__device__ __forceinline__ int ld_tag(const int* p) {
    return __hip_atomic_load(p, __ATOMIC_RELAXED, __HIP_MEMORY_SCOPE_AGENT);
}
__device__ __forceinline__ void st_tag(int* p, int v) {
    __hip_atomic_store(p, v, __ATOMIC_RELAXED, __HIP_MEMORY_SCOPE_AGENT);
}
// data ops: pure group -> sc0 (XCD-local L2 coherent); impure -> sc0 sc1 (LLC)
__device__ __forceinline__ void st_data_f(float* p, float v, int pure) {
    if (pure) asm volatile("global_store_dword %0, %1, off sc0" :: "v"(p), "v"(v) : "memory");
    else      asm volatile("global_store_dword %0, %1, off sc0 sc1" :: "v"(p), "v"(v) : "memory");
}
__device__ __forceinline__ f32x4 ld4_data(const float* p, int pure) {
    f32x4 v;
    if (pure) asm volatile("global_load_dwordx4 %0, %1, off sc0\n\ts_waitcnt vmcnt(0)"
                           : "=&v"(v) : "v"(p) : "memory");
    else      asm volatile("global_load_dwordx4 %0, %1, off sc0 sc1\n\ts_waitcnt vmcnt(0)"
                           : "=&v"(v) : "v"(p) : "memory");
    return v;
}

// ---- Prep: WjhR[j][k]=Wj1[1024+k][j]; b1=bih1+bhh1; Wj2T[v][k]=Wj2[k][v] ----
__global__ void prep_t_kernel(const float* __restrict__ Wj1,
                              const float* __restrict__ bih1,
                              const float* __restrict__ bhh1,
                              const float* __restrict__ Wj2,
                              float* __restrict__ WjhR, float* __restrict__ b1,
                              float* __restrict__ Wj2T) {
    int idx = blockIdx.x * 256 + threadIdx.x;
    if (idx < 163840) {
        int j = idx / 320, k = idx - j * 320;
        WjhR[idx] = Wj1[(size_t)(1024 + k) * JHD + j];
        return;
    }
    int i2 = idx - 163840;
    if (i2 < G4) { b1[i2] = bih1[i2] + bhh1[i2]; return; }
    int e = i2 - G4;
    if (e < VV * JHD) {
        int v = e >> 9, k = e & 511;
        Wj2T[e] = Wj2[(size_t)k * VV + v];
    }
}

// ---- Prep: EP[v][j] = embed[v]@Wih0[j,:] + bih0[j]+bhh0[j]; row 28 = bias only
__global__ void ep_kernel(const float* __restrict__ embed,
                          const float* __restrict__ Wih0,
                          const float* __restrict__ bih0,
                          const float* __restrict__ bhh0,
                          float* __restrict__ EP) {
    __shared__ __align__(16) float es[HH];
    int v = blockIdx.x;
    for (int k = threadIdx.x; k < HH; k += 256)
        es[k] = (v < VV - 1) ? embed[v * HH + k] : 0.0f;
    __syncthreads();
    for (int j = threadIdx.x; j < G4; j += 256) {
        float acc = bih0[j] + bhh0[j];
        if (v < VV - 1) {
            const float4* wr = (const float4*)(Wih0 + (size_t)j * HH);
            const float4* ev = (const float4*)es;
            #pragma unroll 4
            for (int k4 = 0; k4 < HH / 4; ++k4) {
                float4 w = wr[k4], e = ev[k4];
                acc += w.x * e.x + w.y * e.y + w.z * e.z + w.w * e.w;
            }
        }
        EP[v * G4 + j] = acc;
    }
}

// ---- Encoder + F_proj fused ----
__global__ __launch_bounds__(512) void enc_fproj_kernel(
    const float* __restrict__ x, const float* __restrict__ Wenc,
    const float* __restrict__ benc, const float* __restrict__ Wj1,
    const float* __restrict__ bj1,
    float* __restrict__ logits_out, float* __restrict__ Fproj) {
    __shared__ float xs[8][F_IN];
    __shared__ float ls[8][E_DIM];
    int row0 = blockIdx.x * 8;
    int tid = threadIdx.x;
    for (int i = tid; i < 8 * F_IN; i += 512)
        xs[i / F_IN][i % F_IN] = x[(size_t)row0 * F_IN + i];
    __syncthreads();
    for (int j = tid; j < E_DIM; j += 512) {
        float acc[8];
        float bv = benc[j];
        #pragma unroll
        for (int r = 0; r < 8; ++r) acc[r] = bv;
        for (int k = 0; k < F_IN; ++k) {
            float w = Wenc[(size_t)k * E_DIM + j];
            #pragma unroll
            for (int r = 0; r < 8; ++r) acc[r] += xs[r][k] * w;
        }
        #pragma unroll
        for (int r = 0; r < 8; ++r) {
            ls[r][j] = acc[r];
            logits_out[(size_t)(row0 + r) * E_DIM + j] = acc[r];
        }
    }
    __syncthreads();
    {
        int j = tid;
        float acc[8];
        float bv = bj1[j];
        #pragma unroll
        for (int r = 0; r < 8; ++r) acc[r] = bv;
        for (int k = 0; k < E_DIM; ++k) {
            float w = Wj1[(size_t)k * JHD + j];
            #pragma unroll
            for (int r = 0; r < 8; ++r) acc[r] += ls[r][k] * w;
        }
        #pragma unroll
        for (int r = 0; r < 8; ++r) Fproj[(size_t)(row0 + r) * JHD + j] = acc[r];
    }
}

// ---- Init: zero sync; labels=-1; out_lens passthrough ----
__global__ void init_kernel(const int* __restrict__ lens, float* ws,
                            float* __restrict__ out_lens_out,
                            float* __restrict__ labels_out) {
    int tid = threadIdx.x;
    int* sync = (int*)(ws + OFF_SYNC);
    for (int i = tid; i < 2048; i += 1024) sync[i] = 0;
    for (int i = tid; i < BB * LBUF; i += 1024) labels_out[i] = -1.0f;
    if (tid < BB) out_lens_out[tid] = (float)lens[tid];
}

// ---- 8 per-XCD groups x 20 roles, deadlock-free formation, dual-scope data ----
__global__ __launch_bounds__(1024) void decode_persistent(
    const int* __restrict__ lens,
    const float* __restrict__ Fproj,
    const float* __restrict__ W0,    // Whh0 [1280][320]
    const float* __restrict__ W1a,   // Wih1 [1280][320]
    const float* __restrict__ W1b,   // Whh1 [1280][320]
    const float* __restrict__ WjhR,  // [512][320]
    const float* __restrict__ Wj2T,  // [29][512]
    const float* __restrict__ EP, const float* __restrict__ b1,
    const float* __restrict__ bj2,
    float* MA, float* MB, float* JH, int* syncw,
    float* __restrict__ labels_out, float* __restrict__ counts_out) {

    const int tid = threadIdx.x;
    int* cntw = syncw;          // [8], stride 16 ints
    int* arrw = syncw + 128;
    int* tags = syncw + 256;    // [8][3][32]

    // ---------- formation: ticket local XCD, rendezvous, fill deficits ----------
    __shared__ int sGrp, sRole, sPure;
    if (tid == 0) {
        unsigned xr;
        asm volatile("s_getreg_b32 %0, hwreg(HW_REG_XCC_ID)" : "=s"(xr));
        int xcc = (int)(xr & 7u);
        int tkt = atomicAdd(cntw + xcc * 16, 1);
        asm volatile("s_waitcnt vmcnt(0)" ::: "memory");
        atomicAdd(arrw, 1);
        while (__hip_atomic_load(arrw, __ATOMIC_RELAXED, __HIP_MEMORY_SCOPE_AGENT) < NBLK) { }
        int c[8];
        #pragma unroll
        for (int h = 0; h < 8; ++h)
            c[h] = __hip_atomic_load(cntw + h * 16, __ATOMIC_RELAXED,
                                     __HIP_MEMORY_SCOPE_AGENT);
        int grp, role;
        if (tkt < RPG) { grp = xcc; role = tkt; }
        else {
            int ov = tkt - RPG;
            for (int h = 0; h < xcc; ++h) ov += max(0, c[h] - RPG);
            grp = -1; role = 0;
            int acc = 0;
            for (int g2 = 0; g2 < 8; ++g2) {
                int granted = min(c[g2], RPG);
                int d = RPG - granted;
                if (grp < 0 && ov < acc + d) { grp = g2; role = granted + (ov - acc); }
                acc += d;
            }
        }
        sGrp = grp; sRole = role;
        sPure = (c[grp] >= RPG) ? 1 : 0;
    }
    __syncthreads();
    const int grp = sGrp, role = sRole, pure = sPure;

    float* MAg = MA + grp * 640;
    float* MBg = MB + grp * 640;
    float* JHg = JH + grp * 1024;
    int* tagA = tags + grp * 96;
    int* tagB = tagA + 32;
    int* tagC = tagA + 64;

    extern __shared__ float dyn[];
    float* h0c = dyn;            // [2][320]
    float* h1c = dyn + 640;
    float* h0p = dyn + 1280;
    float* h1p = dyn + 1920;
    float* jhl = dyn + 2560;     // [2][512]

    __shared__ float gA[128], gB[128], lgL[64];
    __shared__ int lastL[2], cntL[2], contL[2], lenL[2], emitL[2];

    for (int i = tid; i < 640; i += 1024) { h0c[i] = 0.f; h1c[i] = 0.f; }
    if (tid < 2) {
        lastL[tid] = BLANKV; cntL[tid] = 0; contL[tid] = 0;
        lenL[tid] = lens[2 * grp + tid];
    }
    __syncthreads();
    const int maxL = max(lenL[0], lenL[1]);

    // matvec lanes: item(b0) | ks(b1-3) | r(b4-9)
    const int item = tid & 1;
    const int ks   = (tid >> 1) & 7;
    const int r    = tid >> 4;            // 0..63 local gate row
    const int gg   = r >> 4, rl = r & 15;
    const int hrow = role * HR + rl;      // 0..319
    const int kf   = ks * 40;
    const size_t wrow = (size_t)(gg * HH + hrow) * HH + kf;

    // activation threads: tid<32 -> (it=tid&1, hr=tid>>1)
    float c0cur = 0.f, c1cur = 0.f, c0p = 0.f, c1p = 0.f;

    for (int slot = 0; slot < 3 * maxL; ++slot) {
        const int t = slot / 3;
        const int s = slot - t * 3;
        const int e = slot + 1;

        // ===== Phase A: gates0 = Whh0@h0c (+EP); gB = Whh1@h1c partial =====
        {
            float a0 = 0.f, ab = 0.f;
            const f32x4* h0 = (const f32x4*)(h0c + item * HH + kf);
            const f32x4* h1 = (const f32x4*)(h1c + item * HH + kf);
            #pragma unroll
            for (int u = 0; u < 10; ++u) {
                f32x4 w  = *(const f32x4*)(W0 + wrow + u * 4);
                f32x4 h  = h0[u];
                a0 += w[0]*h[0] + w[1]*h[1] + w[2]*h[2] + w[3]*h[3];
                f32x4 w2 = *(const f32x4*)(W1b + wrow + u * 4);
                f32x4 h2 = h1[u];
                ab += w2[0]*h2[0] + w2[1]*h2[1] + w2[2]*h2[2] + w2[3]*h2[3];
            }
            a0 += __shfl_xor(a0, 2); a0 += __shfl_xor(a0, 4); a0 += __shfl_xor(a0, 8);
            ab += __shfl_xor(ab, 2); ab += __shfl_xor(ab, 4); ab += __shfl_xor(ab, 8);
            if (ks == 0) {
                gA[item * 64 + r] = a0 + EP[(size_t)lastL[item] * G4 + gg * HH + hrow];
                gB[item * 64 + r] = ab;
            }
        }
        __syncthreads();
        if (tid < 32) {
            int it = tid & 1, hr = tid >> 1;
            float xi = gA[it * 64 + hr];
            float xf = gA[it * 64 + 16 + hr];
            float xg = gA[it * 64 + 32 + hr];
            float xo = gA[it * 64 + 48 + hr];
            c0p = sigmoidf_(xf) * c0cur + sigmoidf_(xi) * tanhf(xg);
            st_data_f(MAg + it * HH + role * HR + hr, sigmoidf_(xo) * tanhf(c0p), pure);
        }
        asm volatile("s_waitcnt vmcnt(0)" ::: "memory");
        __syncthreads();
        if (tid == 0) st_tag(tagA + role, e);

        // ===== poll A (20 tags, one line) + stage MA -> h0p =====
        if (tid < 64) {
            while (__ballot((tid < RPG) && (ld_tag(tagA + tid) < e)) != 0ull) { }
        }
        __syncthreads();
        if (tid < 160) {
            f32x4 v = ld4_data(MAg + tid * 4, pure);
            int it = tid / 80, k = tid * 4 - it * 320;
            *(f32x4*)(h0p + it * HH + k) = v;
        }
        __syncthreads();

        // ===== Phase B: gates1 = Wih1@h0p + gB + b1 =====
        {
            float a1 = 0.f;
            const f32x4* hv = (const f32x4*)(h0p + item * HH + kf);
            #pragma unroll
            for (int u = 0; u < 10; ++u) {
                f32x4 w = *(const f32x4*)(W1a + wrow + u * 4);
                f32x4 h = hv[u];
                a1 += w[0]*h[0] + w[1]*h[1] + w[2]*h[2] + w[3]*h[3];
            }
            a1 += __shfl_xor(a1, 2); a1 += __shfl_xor(a1, 4); a1 += __shfl_xor(a1, 8);
            if (ks == 0)
                gA[item * 64 + r] = a1 + gB[item * 64 + r] + b1[gg * HH + hrow];
        }
        __syncthreads();
        if (tid < 32) {
            int it = tid & 1, hr = tid >> 1;
            float xi = gA[it * 64 + hr];
            float xf = gA[it * 64 + 16 + hr];
            float xg = gA[it * 64 + 32 + hr];
            float xo = gA[it * 64 + 48 + hr];
            c1p = sigmoidf_(xf) * c1cur + sigmoidf_(xi) * tanhf(xg);
            st_data_f(MBg + it * HH + role * HR + hr, sigmoidf_(xo) * tanhf(c1p), pure);
        }
        asm volatile("s_waitcnt vmcnt(0)" ::: "memory");
        __syncthreads();
        if (tid == 0) st_tag(tagB + role, e);

        // ===== poll B + stage MB -> h1p =====
        if (tid < 64) {
            while (__ballot((tid < RPG) && (ld_tag(tagB + tid) < e)) != 0ull) { }
        }
        __syncthreads();
        if (tid < 160) {
            f32x4 v = ld4_data(MBg + tid * 4, pure);
            int it = tid / 80, k = tid * 4 - it * 320;
            *(f32x4*)(h1p + it * HH + k) = v;
        }
        __syncthreads();

        // ===== Phase C (roles 0..15): jh = relu(Fproj + Wjh@h1p) =====
        if (role < CROLES && tid < 512) {
            int jl = tid >> 4;                   // 0..31
            int jg2 = role * JR + jl;            // 0..511
            float a = 0.f;
            const f32x4* hv = (const f32x4*)(h1p + item * HH + kf);
            const float* wc = WjhR + (size_t)jg2 * HH + kf;
            #pragma unroll
            for (int u = 0; u < 10; ++u) {
                f32x4 w = *(const f32x4*)(wc + u * 4);
                f32x4 h = hv[u];
                a += w[0]*h[0] + w[1]*h[1] + w[2]*h[2] + w[3]*h[3];
            }
            a += __shfl_xor(a, 2); a += __shfl_xor(a, 4); a += __shfl_xor(a, 8);
            if (ks == 0) {
                float fp = Fproj[((size_t)(2 * grp + item) * TT + t) * JHD + jg2];
                st_data_f(JHg + item * JHD + jg2, fmaxf(a + fp, 0.f), pure);
            }
        }
        asm volatile("s_waitcnt vmcnt(0)" ::: "memory");
        __syncthreads();
        if (role < CROLES && tid == 0) st_tag(tagC + role, e);

        // ===== poll C (16 tags) + stage JH -> jhl =====
        if (tid < 64) {
            while (__ballot((tid < CROLES) && (ld_tag(tagC + tid) < e)) != 0ull) { }
        }
        __syncthreads();
        if (tid < 256) {
            f32x4 v = ld4_data(JHg + tid * 4, pure);
            int it = tid / 128, k = tid * 4 - it * 512;
            *(f32x4*)(jhl + it * JHD + k) = v;
        }
        __syncthreads();

        // ===== Phase D (replicated): logits + argmax + commit =====
        if (tid < 928) {
            int k4 = tid & 15, it2 = (tid >> 4) & 1, v = tid >> 5;  // v 0..28
            const float* wv = Wj2T + (size_t)v * JHD + k4 * 32;
            const f32x4* hj = (const f32x4*)(jhl + it2 * JHD + k4 * 32);
            float a = 0.f;
            #pragma unroll
            for (int u2 = 0; u2 < 8; ++u2) {
                f32x4 w = *(const f32x4*)(wv + u2 * 4);
                f32x4 h = hj[u2];
                a += w[0]*h[0] + w[1]*h[1] + w[2]*h[2] + w[3]*h[3];
            }
            a += __shfl_xor(a, 1); a += __shfl_xor(a, 2);
            a += __shfl_xor(a, 4); a += __shfl_xor(a, 8);
            if (k4 == 0) lgL[it2 * 32 + v] = a + bj2[v];
        }
        __syncthreads();
        if (tid < 2) {
            float best = lgL[tid * 32];
            int k = 0;
            #pragma unroll
            for (int v = 1; v < VV; ++v) {
                float x = lgL[tid * 32 + v];
                if (x > best) { best = x; k = v; }
            }
            bool active = (t < lenL[tid]) && (s == 0 || contL[tid]);
            bool emit = active && (k != BLANKV);
            emitL[tid] = emit ? 1 : 0;
            if (emit) {
                if (role == 0)
                    labels_out[(size_t)(2 * grp + tid) * LBUF + cntL[tid]] = (float)k;
                cntL[tid]++; lastL[tid] = k; contL[tid] = 1;
            } else {
                contL[tid] = 0;
            }
        }
        __syncthreads();
        // commit: LDS copy of pending state; private c registers
        if (tid < 640) {
            int it = tid / 320, k = tid - it * 320;
            if (emitL[it]) {
                h0c[it * HH + k] = h0p[it * HH + k];
                h1c[it * HH + k] = h1p[it * HH + k];
            }
        }
        if (tid < 32 && emitL[tid & 1]) { c0cur = c0p; c1cur = c1p; }
        __syncthreads();
    }

    if (role == 0 && tid < 2) counts_out[2 * grp + tid] = (float)cntL[tid];
}

extern "C" void kernel_launch(void* const* d_in, const int* in_sizes, int n_in,
                              void* d_out, int out_size, void* d_ws, size_t ws_size,
                              hipStream_t stream) {
    const float* x      = (const float*)d_in[0];
    const int*   lens   = (const int*)d_in[1];
    const float* Wenc   = (const float*)d_in[2];
    const float* benc   = (const float*)d_in[3];
    const float* embed  = (const float*)d_in[4];
    const float* Wih0   = (const float*)d_in[5];
    const float* Whh0   = (const float*)d_in[6];
    const float* bih0   = (const float*)d_in[7];
    const float* bhh0   = (const float*)d_in[8];
    const float* Wih1   = (const float*)d_in[9];
    const float* Whh1   = (const float*)d_in[10];
    const float* bih1   = (const float*)d_in[11];
    const float* bhh1   = (const float*)d_in[12];
    const float* Wj1    = (const float*)d_in[13];
    const float* bj1    = (const float*)d_in[14];
    const float* Wj2    = (const float*)d_in[15];
    const float* bj2    = (const float*)d_in[16];

    float* out = (float*)d_out;
    float* logits_out   = out;
    float* out_lens_out = out + (size_t)BB * TT * E_DIM;
    float* labels_out   = out_lens_out + BB;
    float* counts_out   = labels_out + (size_t)BB * LBUF;

    float* ws    = (float*)d_ws;
    float* Fproj = ws + OFF_FPROJ;
    float* WjhR  = ws + OFF_WJHR;
    float* EP    = ws + OFF_EP;
    float* b1    = ws + OFF_B1;
    float* Wj2T  = ws + OFF_WJ2T;
    float* MA    = ws + OFF_MA;
    float* MB    = ws + OFF_MB;
    float* JH    = ws + OFF_JH;
    int*   syncw = (int*)(ws + OFF_SYNC);

    // Force 1 block/CU (purity of round-robin XCD distribution)
    const int dynBytes = 84 * 1024;
    hipFuncSetAttribute((const void*)decode_persistent,
                        hipFuncAttributeMaxDynamicSharedMemorySize, dynBytes);

    {
        int total = 163840 + G4 + VV * JHD;
        prep_t_kernel<<<(total + 255) / 256, 256, 0, stream>>>(
            Wj1, bih1, bhh1, Wj2, WjhR, b1, Wj2T);
    }
    ep_kernel<<<VV, 256, 0, stream>>>(embed, Wih0, bih0, bhh0, EP);
    enc_fproj_kernel<<<(BB * TT) / 8, 512, 0, stream>>>(x, Wenc, benc, Wj1, bj1,
                                                        logits_out, Fproj);
    init_kernel<<<1, 1024, 0, stream>>>(lens, ws, out_lens_out, labels_out);
    decode_persistent<<<NBLK, 1024, dynBytes, stream>>>(
        lens, Fproj, Whh0, Wih1, Whh1, WjhR, Wj2T, EP, b1, bj2,
        MA, MB, JH, syncw, labels_out, counts_out);
}